// Round 9
// baseline (207.503 us; speedup 1.0000x reference)
//
#include <hip/hip_runtime.h>
#include <math.h>

#define B 16
#define N 10000
#define E 160000
#define CAP 64   // per-dst bucket capacity; deg ~ Poisson(16), P(deg>64) ~ 1e-19

// float -> bf16 (RNE) stored as ushort
__device__ __forceinline__ ushort f2bf(float v) {
    uint u = __float_as_uint(v);
    u = (u + 0x7fffu + ((u >> 16) & 1u)) >> 16;
    return (ushort)u;
}
__device__ __forceinline__ float bf2f(ushort u) { return __uint_as_float(((uint)u) << 16); }
__device__ __forceinline__ float bf2f_lo(uint u) { return __uint_as_float(u << 16); }
__device__ __forceinline__ float bf2f_hi(uint u) { return __uint_as_float(u & 0xffff0000u); }
// bucket payload: (ew_q18 << 14) | src ; decode with midpoint
__device__ __forceinline__ float dec_ew(uint u) {
    return ((float)(u >> 14) + 0.5f) * (1.0f / 262144.0f);
}

// ---------------------------------------------------------------------------
// Fused prep (proven R8 form, minus the now-unneeded w2T transpose):
//  A) edge bucketing, one edge per thread (2E=320K < 524K threads)
//  B) grid-stride block-per-node row precompute: 256 thr = 16 b x 16 o,
//     X + w1 staged in LDS, ONE (po,py) pair per thread (~32 VGPR).
//   y[r=n*16+b][o]  = sum_c amp[c]*x[n,b,c]*w1[32+c][o]   (bf16)
//   xpart[r][o]     = sum_c x[n,b,c]*w1[c][o] + b1[o]     (fp32)
//   gi[r], gj[r]    = gate dots (16-lane shuffle reduce)
// ---------------------------------------------------------------------------
__global__ __launch_bounds__(256, 8)
void prep_fused_kernel(const float* __restrict__ X,
                       const float* __restrict__ gate_w1,   // (65)
                       const float* __restrict__ amp_w1,    // (32)
                       const float* __restrict__ b1,        // (16)
                       const int* __restrict__ ei1, const float* __restrict__ ew1,
                       const int* __restrict__ ei2, const float* __restrict__ ew2,
                       const float* __restrict__ w1,        // (64,16)
                       ushort* __restrict__ yt,             // (N*16,16) bf16
                       float* __restrict__ xpart,           // (N*16,16) fp32
                       float* __restrict__ gi, float* __restrict__ gj,
                       int* __restrict__ bcount1, uint* __restrict__ bucket1,
                       int* __restrict__ bcount2, uint* __restrict__ bucket2) {
    __shared__ __align__(16) float s_w1[64 * 16];     // [c][o], 4 KB
    __shared__ float s_x[16][33];                     // [b][c], pad 33
    __shared__ float s_py[16][17];                    // [b][o], pad 17

    int tid = threadIdx.x;
    int gtid = blockIdx.x * 256 + tid;

    // Phase A: edge bucketing (one item per thread)
    if (gtid < 2 * E) {
        if (gtid < E) {
            int t = gtid;
            int d = ei1[E + t];
            int pos = atomicAdd(&bcount1[d], 1);
            if (pos < CAP) {
                uint q = (uint)(ew1[t] * 262144.0f);
                if (q > 262143u) q = 262143u;
                bucket1[d * CAP + pos] = (q << 14) | (uint)ei1[t];
            }
        } else {
            int e = gtid - E;
            int d = ei2[E + e];
            int pos = atomicAdd(&bcount2[d], 1);
            if (pos < CAP) {
                uint q = (uint)(ew2[e] * 262144.0f);
                if (q > 262143u) q = 262143u;
                bucket2[d * CAP + pos] = (q << 14) | (uint)ei2[e];
            }
        }
    }

    // Phase B: block-per-node row precompute, grid-stride (~5 nodes/block).
    {   // stage w1 once: 1 float4 per thread
        int i = tid * 4;
        *(float4*)&s_w1[i] = *(const float4*)&w1[i];
    }
    int b = tid >> 4, o = tid & 15;
    for (int n = blockIdx.x; n < N; n += gridDim.x) {
        __syncthreads();    // also protects s_x/s_py reuse across iterations
        {   // stage X: 16-lane group per row, float2 each (128B/row)
            int bb = tid >> 4, c2 = (tid & 15) * 2;
            float2 v = *(const float2*)(X + ((size_t)bb * N + n) * 32 + c2);
            s_x[bb][c2] = v.x; s_x[bb][c2 + 1] = v.y;
        }
        __syncthreads();

        float po = b1[o], py = 0.f;
        #pragma unroll
        for (int c = 0; c < 32; ++c) {
            float xa = s_x[b][c];                 // broadcast within o-group
            po += xa * s_w1[c * 16 + o];
            py += amp_w1[c] * xa * s_w1[(32 + c) * 16 + o];
        }
        // gate dots: thread covers channels o and o+16, reduce over 16 lanes
        float pi = s_x[b][o] * gate_w1[o]      + s_x[b][o + 16] * gate_w1[o + 16];
        float pj = s_x[b][o] * gate_w1[32 + o] + s_x[b][o + 16] * gate_w1[48 + o];
        #pragma unroll
        for (int off = 8; off; off >>= 1) {
            pi += __shfl_xor(pi, off, 16);
            pj += __shfl_xor(pj, off, 16);
        }
        int r = n * 16 + b;
        xpart[(size_t)r * 16 + o] = po;           // 1KB/node, fully coalesced
        s_py[b][o] = py;
        if (o == 0) { gi[r] = pi; gj[r] = pj; }
        __syncthreads();

        if (tid < 64) {   // pack y rows: 4 threads/row, uint2 each
            int bb = tid >> 2, j = tid & 3;
            uint lo = (uint)f2bf(s_py[bb][4 * j])     | ((uint)f2bf(s_py[bb][4 * j + 1]) << 16);
            uint hi = (uint)f2bf(s_py[bb][4 * j + 2]) | ((uint)f2bf(s_py[bb][4 * j + 3]) << 16);
            ((uint2*)yt)[(size_t)(n * 16 + bb) * 4 + j] = make_uint2(lo, hi);
        }
    }
}

// ---------------------------------------------------------------------------
// Layer 1: WAVE-PER-NODE, zero LDS, zero barriers (proven R7/R8). Block = 4
// waves = 4 independent nodes. Lane (og=l&1, b=(l>>1)&15, h=l>>5): coef
// fused into gather loop; bucket read broadcasts, y4 read = one 512B
// segment per (k, half-wave). Reduce = 1 shuffle step.
// ---------------------------------------------------------------------------
__global__ __launch_bounds__(256, 8)
void agg1_kernel(const uint4* __restrict__ y4,      // (N*16) rows x 32B
                 const float* __restrict__ xpart,   // (N*16,16) fp32
                 const float* __restrict__ gi,
                 const float* __restrict__ gj,
                 const int* __restrict__ bcount,
                 const uint* __restrict__ bucket,
                 const float* __restrict__ gate_w,   // (65), [64]=wge
                 const float* __restrict__ gate_b,
                 const float* __restrict__ gate_w2,  // (33)
                 ushort* __restrict__ htb,
                 float* __restrict__ gi2, float* __restrict__ gj2) {
    int tid = threadIdx.x;
    int wv = tid >> 6, l = tid & 63;
    int n = blockIdx.x * 4 + wv;           // grid = N/4 exact
    int og = l & 1, b = (l >> 1) & 15, h = l >> 5;

    int cnt = bcount[n];
    int deg = cnt < CAP ? cnt : CAP;
    float wge = gate_w[64];
    float gib = gi[n * 16 + b] + gate_b[0];
    const uint* __restrict__ eb = bucket + (size_t)n * CAP;

    float a0 = 0.f, a1 = 0.f, a2 = 0.f, a3 = 0.f;
    float a4 = 0.f, a5 = 0.f, a6 = 0.f, a7 = 0.f;
    for (int k = h; k < deg; k += 2) {
        uint pr = eb[k];                   // broadcast within half-wave
        uint src = pr & 0x3FFFu;
        float w = dec_ew(pr);
        float z = gib + gj[src * 16 + b] + w * wge;
        float cc = w / (1.0f + __expf(-z));
        uint4 u = y4[src * 32u + (uint)b * 2u + og];
        a0 += cc * bf2f_lo(u.x); a1 += cc * bf2f_hi(u.x);
        a2 += cc * bf2f_lo(u.y); a3 += cc * bf2f_hi(u.y);
        a4 += cc * bf2f_lo(u.z); a5 += cc * bf2f_hi(u.z);
        a6 += cc * bf2f_lo(u.w); a7 += cc * bf2f_hi(u.w);
    }
    // reduce over h (lane bit 5)
    a0 += __shfl_xor(a0, 32, 64); a1 += __shfl_xor(a1, 32, 64);
    a2 += __shfl_xor(a2, 32, 64); a3 += __shfl_xor(a3, 32, 64);
    a4 += __shfl_xor(a4, 32, 64); a5 += __shfl_xor(a5, 32, 64);
    a6 += __shfl_xor(a6, 32, 64); a7 += __shfl_xor(a7, 32, 64);

    if (h == 0) {   // lanes 0..31: (b, og)
        float inv = 1.0f / fmaxf((float)cnt, 1.0f);
        size_t xb = ((size_t)n * 16 + b) * 16 + 8 * og;
        float4 xp0 = *(const float4*)&xpart[xb];
        float4 xp1 = *(const float4*)&xpart[xb + 4];
        float v0 = xp0.x + inv * a0, v1 = xp0.y + inv * a1;
        float v2 = xp0.z + inv * a2, v3 = xp0.w + inv * a3;
        float v4 = xp1.x + inv * a4, v5 = xp1.y + inv * a5;
        float v6 = xp1.z + inv * a6, v7 = xp1.w + inv * a7;
        v0 = v0 > 0.f ? v0 : 0.01f * v0;  v1 = v1 > 0.f ? v1 : 0.01f * v1;
        v2 = v2 > 0.f ? v2 : 0.01f * v2;  v3 = v3 > 0.f ? v3 : 0.01f * v3;
        v4 = v4 > 0.f ? v4 : 0.01f * v4;  v5 = v5 > 0.f ? v5 : 0.01f * v5;
        v6 = v6 > 0.f ? v6 : 0.01f * v6;  v7 = v7 > 0.f ? v7 : 0.01f * v7;
        uint4 pk;
        pk.x = (uint)f2bf(v0) | ((uint)f2bf(v1) << 16);
        pk.y = (uint)f2bf(v2) | ((uint)f2bf(v3) << 16);
        pk.z = (uint)f2bf(v4) | ((uint)f2bf(v5) << 16);
        pk.w = (uint)f2bf(v6) | ((uint)f2bf(v7) << 16);
        ((uint4*)htb)[(size_t)n * 32 + b * 2 + og] = pk;   // 512B coalesced
        int ob = 8 * og;
        float pi = v0 * gate_w2[ob]     + v1 * gate_w2[ob + 1]
                 + v2 * gate_w2[ob + 2] + v3 * gate_w2[ob + 3]
                 + v4 * gate_w2[ob + 4] + v5 * gate_w2[ob + 5]
                 + v6 * gate_w2[ob + 6] + v7 * gate_w2[ob + 7];
        float pj = v0 * gate_w2[16 + ob]     + v1 * gate_w2[16 + ob + 1]
                 + v2 * gate_w2[16 + ob + 2] + v3 * gate_w2[16 + ob + 3]
                 + v4 * gate_w2[16 + ob + 4] + v5 * gate_w2[16 + ob + 5]
                 + v6 * gate_w2[16 + ob + 6] + v7 * gate_w2[16 + ob + 7];
        pi += __shfl_xor(pi, 1, 64);       // og pair, both lanes in h==0
        pj += __shfl_xor(pj, 1, 64);
        if (og == 0) { gi2[n * 16 + b] = pi; gj2[n * 16 + b] = pj; }
    }
}

// ---------------------------------------------------------------------------
// Layer 2 (R8 post-mortem: 11.7M LDS bank conflicts from [o][kk] w2T reads).
// w2 staged in its NATIVE [kk][o] layout (no transpose anywhere), stride 36.
// s_in[nl][b][36]: kk 0..15 = self h, 16..31 = feat. Dense phase: thread
// (o4 = tid&7 -> 4 outputs, bb = (tid>>3)&15, half = tid>>7 -> 2 nodes);
// 48 conflict-free b128 reads/thread, weights shared across the 2 nodes.
// ---------------------------------------------------------------------------
__global__ __launch_bounds__(256, 8)
void agg2_kernel(const uint4* __restrict__ htb4,    // (N*16) rows x 32B
                 const float* __restrict__ gi,
                 const float* __restrict__ gj,
                 const int* __restrict__ bcount,
                 const uint* __restrict__ bucket,
                 const float* __restrict__ gate_w,   // (33), [32]=wge
                 const float* __restrict__ gate_b,
                 const float* __restrict__ amp_w,    // (16)
                 const float* __restrict__ w2,       // (32,32) [kk][o] native
                 const float* __restrict__ b2,       // (32)
                 float* __restrict__ out) {
    __shared__ __align__(16) float s_w2[32 * 36];       // [kk][o], 144B rows
    __shared__ __align__(16) float s_in[4][16][36];     // [nl][b][kk], 144B rows

    int tid = threadIdx.x;
    int n0 = blockIdx.x * 4;

    {   // stage w2 native layout: 256 float4 copies
        int kk = tid >> 3, o4g = tid & 7;
        *(float4*)&s_w2[kk * 36 + 4 * o4g] = *(const float4*)&w2[kk * 32 + 4 * o4g];
    }
    if (tid < 128) {   // self features -> s_in[..][0..15], 4 nodes x 32 uint4
        int nl = tid >> 5, idx = tid & 31;
        uint4 u = htb4[(size_t)(n0 + nl) * 32 + idx];
        int b = idx >> 1, cb = (idx & 1) * 8;
        float4 f0, f1;
        f0.x = bf2f_lo(u.x); f0.y = bf2f_hi(u.x);
        f0.z = bf2f_lo(u.y); f0.w = bf2f_hi(u.y);
        f1.x = bf2f_lo(u.z); f1.y = bf2f_hi(u.z);
        f1.z = bf2f_lo(u.w); f1.w = bf2f_hi(u.w);
        *(float4*)&s_in[nl][b][cb]     = f0;
        *(float4*)&s_in[nl][b][cb + 4] = f1;
    }
    __syncthreads();

    // per-wave fused coef+gather (unchanged from R8)
    int wv = tid >> 6, l = tid & 63;
    int n = n0 + wv;
    int og = l & 1, b = (l >> 1) & 15, h = l >> 5;
    int cnt = bcount[n];
    int deg = cnt < CAP ? cnt : CAP;
    float wge = gate_w[32];
    float gib = gi[n * 16 + b] + gate_b[0];
    const uint* __restrict__ eb = bucket + (size_t)n * CAP;

    float a0 = 0.f, a1 = 0.f, a2 = 0.f, a3 = 0.f;
    float a4 = 0.f, a5 = 0.f, a6 = 0.f, a7 = 0.f;
    for (int k = h; k < deg; k += 2) {
        uint pr = eb[k];
        uint src = pr & 0x3FFFu;
        float w = dec_ew(pr);
        float z = gib + gj[src * 16 + b] + w * wge;
        float cc = w / (1.0f + __expf(-z));
        uint4 u = htb4[src * 32u + (uint)b * 2u + og];
        a0 += cc * bf2f_lo(u.x); a1 += cc * bf2f_hi(u.x);
        a2 += cc * bf2f_lo(u.y); a3 += cc * bf2f_hi(u.y);
        a4 += cc * bf2f_lo(u.z); a5 += cc * bf2f_hi(u.z);
        a6 += cc * bf2f_lo(u.w); a7 += cc * bf2f_hi(u.w);
    }
    a0 += __shfl_xor(a0, 32, 64); a1 += __shfl_xor(a1, 32, 64);
    a2 += __shfl_xor(a2, 32, 64); a3 += __shfl_xor(a3, 32, 64);
    a4 += __shfl_xor(a4, 32, 64); a5 += __shfl_xor(a5, 32, 64);
    a6 += __shfl_xor(a6, 32, 64); a7 += __shfl_xor(a7, 32, 64);
    if (h == 0) {   // feat -> s_in[wv][b][16 + 8og ..], 2 float4 stores
        float inv = 1.0f / fmaxf((float)cnt, 1.0f);
        int cb = 8 * og;
        float4 f0, f1;
        f0.x = a0 * amp_w[cb]     * inv;  f0.y = a1 * amp_w[cb + 1] * inv;
        f0.z = a2 * amp_w[cb + 2] * inv;  f0.w = a3 * amp_w[cb + 3] * inv;
        f1.x = a4 * amp_w[cb + 4] * inv;  f1.y = a5 * amp_w[cb + 5] * inv;
        f1.z = a6 * amp_w[cb + 6] * inv;  f1.w = a7 * amp_w[cb + 7] * inv;
        *(float4*)&s_in[wv][b][16 + cb]     = f0;
        *(float4*)&s_in[wv][b][16 + cb + 4] = f1;
    }
    __syncthreads();

    // dense 32->32: thread (o4, bb, half); weights shared across 2 nodes.
    {
        int o4 = tid & 7, bb = (tid >> 3) & 15, half = tid >> 7;
        int nlA = half * 2, nlB = half * 2 + 1;
        float4 bias = *(const float4*)&b2[4 * o4];
        float4 acc0 = bias, acc1 = bias;
        #pragma unroll
        for (int k4 = 0; k4 < 8; ++k4) {
            float4 ivA = *(const float4*)&s_in[nlA][bb][4 * k4];
            float4 ivB = *(const float4*)&s_in[nlB][bb][4 * k4];
            float4 w0 = *(const float4*)&s_w2[(4 * k4)     * 36 + 4 * o4];
            float4 w1 = *(const float4*)&s_w2[(4 * k4 + 1) * 36 + 4 * o4];
            float4 wv2 = *(const float4*)&s_w2[(4 * k4 + 2) * 36 + 4 * o4];
            float4 w3 = *(const float4*)&s_w2[(4 * k4 + 3) * 36 + 4 * o4];
            acc0.x += ivA.x * w0.x + ivA.y * w1.x + ivA.z * wv2.x + ivA.w * w3.x;
            acc0.y += ivA.x * w0.y + ivA.y * w1.y + ivA.z * wv2.y + ivA.w * w3.y;
            acc0.z += ivA.x * w0.z + ivA.y * w1.z + ivA.z * wv2.z + ivA.w * w3.z;
            acc0.w += ivA.x * w0.w + ivA.y * w1.w + ivA.z * wv2.w + ivA.w * w3.w;
            acc1.x += ivB.x * w0.x + ivB.y * w1.x + ivB.z * wv2.x + ivB.w * w3.x;
            acc1.y += ivB.x * w0.y + ivB.y * w1.y + ivB.z * wv2.y + ivB.w * w3.y;
            acc1.z += ivB.x * w0.z + ivB.y * w1.z + ivB.z * wv2.z + ivB.w * w3.z;
            acc1.w += ivB.x * w0.w + ivB.y * w1.w + ivB.z * wv2.w + ivB.w * w3.w;
        }
        *(float4*)(out + ((size_t)bb * N + (n0 + nlA)) * 32 + 4 * o4) = acc0;
        *(float4*)(out + ((size_t)bb * N + (n0 + nlB)) * 32 + 4 * o4) = acc1;
    }
}

// ---------------------------------------------------------------------------
extern "C" void kernel_launch(void* const* d_in, const int* in_sizes, int n_in,
                              void* d_out, int out_size, void* d_ws, size_t ws_size,
                              hipStream_t stream) {
    const float* X       = (const float*)d_in[0];
    const int*   ei1     = (const int*)  d_in[1];   // src=ei1, dst=ei1+E
    const float* ew1     = (const float*)d_in[2];
    const int*   ei2     = (const int*)  d_in[4];
    const float* ew2     = (const float*)d_in[5];
    const float* amp_w1  = (const float*)d_in[7];
    const float* gate_w1 = (const float*)d_in[8];
    const float* gate_b1 = (const float*)d_in[9];
    const float* w1      = (const float*)d_in[10];
    const float* b1      = (const float*)d_in[11];
    const float* amp_w2  = (const float*)d_in[12];
    const float* gate_w2 = (const float*)d_in[13];
    const float* gate_b2 = (const float*)d_in[14];
    const float* w2      = (const float*)d_in[15];
    const float* b2      = (const float*)d_in[16];
    float* out = (float*)d_out;

    // ws layout
    char* p = (char*)d_ws;
    ushort* yt     = (ushort*)p; p += (size_t)N * B * 16 * sizeof(ushort); // 5.12 MB
    ushort* htb    = (ushort*)p; p += (size_t)N * B * 16 * sizeof(ushort); // 5.12 MB
    float* xpart   = (float*)p;  p += (size_t)N * B * 16 * sizeof(float);  // 10.24 MB
    float* gi1     = (float*)p;  p += (size_t)N * B * sizeof(float);
    float* gj1     = (float*)p;  p += (size_t)N * B * sizeof(float);
    float* gi2     = (float*)p;  p += (size_t)N * B * sizeof(float);
    float* gj2     = (float*)p;  p += (size_t)N * B * sizeof(float);
    uint*  bucket1 = (uint*)p;   p += (size_t)N * CAP * sizeof(uint);      // 2.56 MB
    uint*  bucket2 = (uint*)p;   p += (size_t)N * CAP * sizeof(uint);      // 2.56 MB
    int*   bcount1 = (int*)p;    p += (size_t)N * sizeof(int);
    int*   bcount2 = (int*)p;    p += (size_t)N * sizeof(int);

    hipMemsetAsync(bcount1, 0, 2 * (size_t)N * sizeof(int), stream);
    prep_fused_kernel<<<2048, 256, 0, stream>>>(
        X, gate_w1, amp_w1, b1, ei1, ew1, ei2, ew2, w1,
        yt, xpart, gi1, gj1,
        bcount1, bucket1, bcount2, bucket2);

    agg1_kernel<<<N / 4, 256, 0, stream>>>(
        (const uint4*)yt, xpart, gi1, gj1, bcount1, bucket1,
        gate_w1, gate_b1, gate_w2, htb, gi2, gj2);

    agg2_kernel<<<N / 4, 256, 0, stream>>>(
        (const uint4*)htb, gi2, gj2, bcount2, bucket2,
        gate_w2, gate_b2, amp_w2, w2, b2, out);
}

// Round 10
// 172.960 us; speedup vs baseline: 1.1997x; 1.1997x over previous
//
#include <hip/hip_runtime.h>
#include <math.h>

#define B 16
#define N 10000
#define E 160000
#define CAP 64   // per-dst bucket capacity; deg ~ Poisson(16), P(deg>64) ~ 1e-19

// float -> bf16 (RNE) stored as ushort
__device__ __forceinline__ ushort f2bf(float v) {
    uint u = __float_as_uint(v);
    u = (u + 0x7fffu + ((u >> 16) & 1u)) >> 16;
    return (ushort)u;
}
__device__ __forceinline__ float bf2f(ushort u) { return __uint_as_float(((uint)u) << 16); }
__device__ __forceinline__ float bf2f_lo(uint u) { return __uint_as_float(u << 16); }
__device__ __forceinline__ float bf2f_hi(uint u) { return __uint_as_float(u & 0xffff0000u); }
// bucket payload: (ew_q18 << 14) | src ; decode with midpoint
__device__ __forceinline__ float dec_ew(uint u) {
    return ((float)(u >> 14) + 0.5f) * (1.0f / 262144.0f);
}

// ---------------------------------------------------------------------------
// Fused prep (proven R8 form):
//  A) edge bucketing, one edge per thread (2E=320K < 524K threads)
//  B) grid-stride block-per-node row precompute: 256 thr = 16 b x 16 o,
//     X + w1 staged in LDS, ONE (po,py) pair per thread (~32 VGPR).
// ---------------------------------------------------------------------------
__global__ __launch_bounds__(256, 8)
void prep_fused_kernel(const float* __restrict__ X,
                       const float* __restrict__ gate_w1,   // (65)
                       const float* __restrict__ amp_w1,    // (32)
                       const float* __restrict__ b1,        // (16)
                       const int* __restrict__ ei1, const float* __restrict__ ew1,
                       const int* __restrict__ ei2, const float* __restrict__ ew2,
                       const float* __restrict__ w1,        // (64,16)
                       ushort* __restrict__ yt,             // (N*16,16) bf16
                       float* __restrict__ xpart,           // (N*16,16) fp32
                       float* __restrict__ gi, float* __restrict__ gj,
                       int* __restrict__ bcount1, uint* __restrict__ bucket1,
                       int* __restrict__ bcount2, uint* __restrict__ bucket2) {
    __shared__ __align__(16) float s_w1[64 * 16];     // [c][o], 4 KB
    __shared__ float s_x[16][33];                     // [b][c], pad 33
    __shared__ float s_py[16][17];                    // [b][o], pad 17

    int tid = threadIdx.x;
    int gtid = blockIdx.x * 256 + tid;

    // Phase A: edge bucketing (one item per thread)
    if (gtid < 2 * E) {
        if (gtid < E) {
            int t = gtid;
            int d = ei1[E + t];
            int pos = atomicAdd(&bcount1[d], 1);
            if (pos < CAP) {
                uint q = (uint)(ew1[t] * 262144.0f);
                if (q > 262143u) q = 262143u;
                bucket1[d * CAP + pos] = (q << 14) | (uint)ei1[t];
            }
        } else {
            int e = gtid - E;
            int d = ei2[E + e];
            int pos = atomicAdd(&bcount2[d], 1);
            if (pos < CAP) {
                uint q = (uint)(ew2[e] * 262144.0f);
                if (q > 262143u) q = 262143u;
                bucket2[d * CAP + pos] = (q << 14) | (uint)ei2[e];
            }
        }
    }

    // Phase B: block-per-node row precompute, grid-stride (~5 nodes/block).
    {   // stage w1 once: 1 float4 per thread
        int i = tid * 4;
        *(float4*)&s_w1[i] = *(const float4*)&w1[i];
    }
    int b = tid >> 4, o = tid & 15;
    for (int n = blockIdx.x; n < N; n += gridDim.x) {
        __syncthreads();    // also protects s_x/s_py reuse across iterations
        {   // stage X: 16-lane group per row, float2 each (128B/row)
            int bb = tid >> 4, c2 = (tid & 15) * 2;
            float2 v = *(const float2*)(X + ((size_t)bb * N + n) * 32 + c2);
            s_x[bb][c2] = v.x; s_x[bb][c2 + 1] = v.y;
        }
        __syncthreads();

        float po = b1[o], py = 0.f;
        #pragma unroll
        for (int c = 0; c < 32; ++c) {
            float xa = s_x[b][c];                 // broadcast within o-group
            po += xa * s_w1[c * 16 + o];
            py += amp_w1[c] * xa * s_w1[(32 + c) * 16 + o];
        }
        // gate dots: thread covers channels o and o+16, reduce over 16 lanes
        float pi = s_x[b][o] * gate_w1[o]      + s_x[b][o + 16] * gate_w1[o + 16];
        float pj = s_x[b][o] * gate_w1[32 + o] + s_x[b][o + 16] * gate_w1[48 + o];
        #pragma unroll
        for (int off = 8; off; off >>= 1) {
            pi += __shfl_xor(pi, off, 16);
            pj += __shfl_xor(pj, off, 16);
        }
        int r = n * 16 + b;
        xpart[(size_t)r * 16 + o] = po;           // 1KB/node, fully coalesced
        s_py[b][o] = py;
        if (o == 0) { gi[r] = pi; gj[r] = pj; }
        __syncthreads();

        if (tid < 64) {   // pack y rows: 4 threads/row, uint2 each
            int bb = tid >> 2, j = tid & 3;
            uint lo = (uint)f2bf(s_py[bb][4 * j])     | ((uint)f2bf(s_py[bb][4 * j + 1]) << 16);
            uint hi = (uint)f2bf(s_py[bb][4 * j + 2]) | ((uint)f2bf(s_py[bb][4 * j + 3]) << 16);
            ((uint2*)yt)[(size_t)(n * 16 + bb) * 4 + j] = make_uint2(lo, hi);
        }
    }
}

// ---------------------------------------------------------------------------
// Layer 1: WAVE-PER-NODE, zero LDS, zero barriers. R9 post-mortem fix:
// lane-holds-edge (my_pr = bucket[n*CAP + l], one 256B wave-load) + shfl
// broadcast kills the eb->gj/y4 serial memory dependency; dual-slot unroll
// gives 4 independent loads in flight per wave.
// Lane map: og=l&1, b=(l>>1)&15, h=l>>5; slots k=h, h+2 per iter (step 4).
// ---------------------------------------------------------------------------
__global__ __launch_bounds__(256, 8)
void agg1_kernel(const uint4* __restrict__ y4,      // (N*16) rows x 32B
                 const float* __restrict__ xpart,   // (N*16,16) fp32
                 const float* __restrict__ gi,
                 const float* __restrict__ gj,
                 const int* __restrict__ bcount,
                 const uint* __restrict__ bucket,
                 const float* __restrict__ gate_w,   // (65), [64]=wge
                 const float* __restrict__ gate_b,
                 const float* __restrict__ gate_w2,  // (33)
                 ushort* __restrict__ htb,
                 float* __restrict__ gi2, float* __restrict__ gj2) {
    int tid = threadIdx.x;
    int wv = tid >> 6, l = tid & 63;
    int n = blockIdx.x * 4 + wv;           // grid = N/4 exact
    int og = l & 1, b = (l >> 1) & 15, h = l >> 5;

    int cnt = bcount[n];
    int deg = cnt < CAP ? cnt : CAP;
    float wge = gate_w[64];
    float gib = gi[n * 16 + b] + gate_b[0];
    uint my_pr = bucket[(size_t)n * CAP + l];  // lane l holds edge slot l

    float a0 = 0.f, a1 = 0.f, a2 = 0.f, a3 = 0.f;
    float a4 = 0.f, a5 = 0.f, a6 = 0.f, a7 = 0.f;
    for (int k = h; k < deg; k += 4) {     // slots k (valid), k+2 (checked)
        int k1 = k + 2;
        bool v1 = k1 < deg;
        uint pr0 = __shfl(my_pr, k, 64);
        uint pr1 = __shfl(my_pr, v1 ? k1 : k, 64);  // clamp: real finite data
        uint s0 = pr0 & 0x3FFFu, s1 = pr1 & 0x3FFFu;
        float g0 = gj[s0 * 16 + b];
        float g1 = gj[s1 * 16 + b];
        uint4 u0 = y4[s0 * 32u + (uint)b * 2u + og];
        uint4 u1 = y4[s1 * 32u + (uint)b * 2u + og];
        float w0 = dec_ew(pr0), w1 = dec_ew(pr1);
        float c0 = w0 / (1.0f + __expf(-(gib + g0 + w0 * wge)));
        float c1 = v1 ? (w1 / (1.0f + __expf(-(gib + g1 + w1 * wge)))) : 0.f;
        a0 += c0 * bf2f_lo(u0.x) + c1 * bf2f_lo(u1.x);
        a1 += c0 * bf2f_hi(u0.x) + c1 * bf2f_hi(u1.x);
        a2 += c0 * bf2f_lo(u0.y) + c1 * bf2f_lo(u1.y);
        a3 += c0 * bf2f_hi(u0.y) + c1 * bf2f_hi(u1.y);
        a4 += c0 * bf2f_lo(u0.z) + c1 * bf2f_lo(u1.z);
        a5 += c0 * bf2f_hi(u0.z) + c1 * bf2f_hi(u1.z);
        a6 += c0 * bf2f_lo(u0.w) + c1 * bf2f_lo(u1.w);
        a7 += c0 * bf2f_hi(u0.w) + c1 * bf2f_hi(u1.w);
    }
    // reduce over h (lane bit 5)
    a0 += __shfl_xor(a0, 32, 64); a1 += __shfl_xor(a1, 32, 64);
    a2 += __shfl_xor(a2, 32, 64); a3 += __shfl_xor(a3, 32, 64);
    a4 += __shfl_xor(a4, 32, 64); a5 += __shfl_xor(a5, 32, 64);
    a6 += __shfl_xor(a6, 32, 64); a7 += __shfl_xor(a7, 32, 64);

    if (h == 0) {   // lanes 0..31: (b, og)
        float inv = 1.0f / fmaxf((float)cnt, 1.0f);
        size_t xb = ((size_t)n * 16 + b) * 16 + 8 * og;
        float4 xp0 = *(const float4*)&xpart[xb];
        float4 xp1 = *(const float4*)&xpart[xb + 4];
        float v0 = xp0.x + inv * a0, v1 = xp0.y + inv * a1;
        float v2 = xp0.z + inv * a2, v3 = xp0.w + inv * a3;
        float v4 = xp1.x + inv * a4, v5 = xp1.y + inv * a5;
        float v6 = xp1.z + inv * a6, v7 = xp1.w + inv * a7;
        v0 = v0 > 0.f ? v0 : 0.01f * v0;  v1 = v1 > 0.f ? v1 : 0.01f * v1;
        v2 = v2 > 0.f ? v2 : 0.01f * v2;  v3 = v3 > 0.f ? v3 : 0.01f * v3;
        v4 = v4 > 0.f ? v4 : 0.01f * v4;  v5 = v5 > 0.f ? v5 : 0.01f * v5;
        v6 = v6 > 0.f ? v6 : 0.01f * v6;  v7 = v7 > 0.f ? v7 : 0.01f * v7;
        uint4 pk;
        pk.x = (uint)f2bf(v0) | ((uint)f2bf(v1) << 16);
        pk.y = (uint)f2bf(v2) | ((uint)f2bf(v3) << 16);
        pk.z = (uint)f2bf(v4) | ((uint)f2bf(v5) << 16);
        pk.w = (uint)f2bf(v6) | ((uint)f2bf(v7) << 16);
        ((uint4*)htb)[(size_t)n * 32 + b * 2 + og] = pk;   // 512B coalesced
        int ob = 8 * og;
        float pi = v0 * gate_w2[ob]     + v1 * gate_w2[ob + 1]
                 + v2 * gate_w2[ob + 2] + v3 * gate_w2[ob + 3]
                 + v4 * gate_w2[ob + 4] + v5 * gate_w2[ob + 5]
                 + v6 * gate_w2[ob + 6] + v7 * gate_w2[ob + 7];
        float pj = v0 * gate_w2[16 + ob]     + v1 * gate_w2[16 + ob + 1]
                 + v2 * gate_w2[16 + ob + 2] + v3 * gate_w2[16 + ob + 3]
                 + v4 * gate_w2[16 + ob + 4] + v5 * gate_w2[16 + ob + 5]
                 + v6 * gate_w2[16 + ob + 6] + v7 * gate_w2[16 + ob + 7];
        pi += __shfl_xor(pi, 1, 64);       // og pair, both lanes in h==0
        pj += __shfl_xor(pj, 1, 64);
        if (og == 0) { gi2[n * 16 + b] = pi; gj2[n * 16 + b] = pj; }
    }
}

// ---------------------------------------------------------------------------
// Layer 2, BATCH-HALF SLICED (R9: htb 5.12MB > 4MB/XCD L2 -> 60MB FETCH).
// grid = 2*(N/4); bg = slow index -> dispatch-order phase separation; each
// instance gathers only b in [8bg, 8bg+8): active htb slice 2.56MB, L2-fit.
// Slicing is near-free here: only the 256B eb wave-load is duplicated
// (coef exps, self, dense, out all split cleanly by b).
// Gather: lane (og=l&1, bl=(l>>1)&7, q=l>>4 depth 4) + shfl-broadcast +
// dual-slot unroll -> 8 slots / 16 loads in flight per wave.
// Dense: w2 native [kk][o] (R9 conflict fix), thread (o4, bl, nl).
// ---------------------------------------------------------------------------
__global__ __launch_bounds__(256, 8)
void agg2_kernel(const uint4* __restrict__ htb4,    // (N*16) rows x 32B
                 const float* __restrict__ gi,
                 const float* __restrict__ gj,
                 const int* __restrict__ bcount,
                 const uint* __restrict__ bucket,
                 const float* __restrict__ gate_w,   // (33), [32]=wge
                 const float* __restrict__ gate_b,
                 const float* __restrict__ amp_w,    // (16)
                 const float* __restrict__ w2,       // (32,32) [kk][o] native
                 const float* __restrict__ b2,       // (32)
                 float* __restrict__ out) {
    __shared__ __align__(16) float s_w2[32 * 36];       // [kk][o], 144B rows
    __shared__ __align__(16) float s_in[4][8][36];      // [nl][bl][kk]

    int tid = threadIdx.x;
    const int nb = N / 4;                  // 2500
    int bg = blockIdx.x / nb;              // 0..1 slow -> phase separation
    int n0 = (blockIdx.x - bg * nb) * 4;

    {   // stage w2 native layout: 256 float4 copies
        int kk = tid >> 3, o4g = tid & 7;
        *(float4*)&s_w2[kk * 36 + 4 * o4g] = *(const float4*)&w2[kk * 32 + 4 * o4g];
    }
    if (tid < 64) {   // self features: 4 nodes x 8 bl x 2 og (this b-half)
        int nl = tid >> 4, idx = tid & 15;
        uint4 u = htb4[(size_t)(n0 + nl) * 32 + bg * 16 + idx];
        int bl = idx >> 1, cb = (idx & 1) * 8;
        float4 f0, f1;
        f0.x = bf2f_lo(u.x); f0.y = bf2f_hi(u.x);
        f0.z = bf2f_lo(u.y); f0.w = bf2f_hi(u.y);
        f1.x = bf2f_lo(u.z); f1.y = bf2f_hi(u.z);
        f1.z = bf2f_lo(u.w); f1.w = bf2f_hi(u.w);
        *(float4*)&s_in[nl][bl][cb]     = f0;
        *(float4*)&s_in[nl][bl][cb + 4] = f1;
    }
    __syncthreads();

    // per-wave fused coef+gather, shfl-broadcast, q-depth 4 + dual unroll
    int wv = tid >> 6, l = tid & 63;
    int n = n0 + wv;
    int og = l & 1, bl = (l >> 1) & 7, q = l >> 4;
    int b = bg * 8 + bl;
    int cnt = bcount[n];
    int deg = cnt < CAP ? cnt : CAP;
    float wge = gate_w[32];
    float gib = gi[n * 16 + b] + gate_b[0];
    uint my_pr = bucket[(size_t)n * CAP + l];  // lane l holds edge slot l

    float a0 = 0.f, a1 = 0.f, a2 = 0.f, a3 = 0.f;
    float a4 = 0.f, a5 = 0.f, a6 = 0.f, a7 = 0.f;
    for (int k = q; k < deg; k += 8) {     // slots k (valid), k+4 (checked)
        int k1 = k + 4;
        bool v1 = k1 < deg;
        uint pr0 = __shfl(my_pr, k, 64);
        uint pr1 = __shfl(my_pr, v1 ? k1 : k, 64);
        uint s0 = pr0 & 0x3FFFu, s1 = pr1 & 0x3FFFu;
        float g0 = gj[s0 * 16 + b];
        float g1 = gj[s1 * 16 + b];
        uint4 u0 = htb4[s0 * 32u + (uint)b * 2u + og];
        uint4 u1 = htb4[s1 * 32u + (uint)b * 2u + og];
        float w0 = dec_ew(pr0), w1 = dec_ew(pr1);
        float c0 = w0 / (1.0f + __expf(-(gib + g0 + w0 * wge)));
        float c1 = v1 ? (w1 / (1.0f + __expf(-(gib + g1 + w1 * wge)))) : 0.f;
        a0 += c0 * bf2f_lo(u0.x) + c1 * bf2f_lo(u1.x);
        a1 += c0 * bf2f_hi(u0.x) + c1 * bf2f_hi(u1.x);
        a2 += c0 * bf2f_lo(u0.y) + c1 * bf2f_lo(u1.y);
        a3 += c0 * bf2f_hi(u0.y) + c1 * bf2f_hi(u1.y);
        a4 += c0 * bf2f_lo(u0.z) + c1 * bf2f_lo(u1.z);
        a5 += c0 * bf2f_hi(u0.z) + c1 * bf2f_hi(u1.z);
        a6 += c0 * bf2f_lo(u0.w) + c1 * bf2f_lo(u1.w);
        a7 += c0 * bf2f_hi(u0.w) + c1 * bf2f_hi(u1.w);
    }
    // reduce over q (lane bits 4,5)
    a0 += __shfl_xor(a0, 16, 64); a0 += __shfl_xor(a0, 32, 64);
    a1 += __shfl_xor(a1, 16, 64); a1 += __shfl_xor(a1, 32, 64);
    a2 += __shfl_xor(a2, 16, 64); a2 += __shfl_xor(a2, 32, 64);
    a3 += __shfl_xor(a3, 16, 64); a3 += __shfl_xor(a3, 32, 64);
    a4 += __shfl_xor(a4, 16, 64); a4 += __shfl_xor(a4, 32, 64);
    a5 += __shfl_xor(a5, 16, 64); a5 += __shfl_xor(a5, 32, 64);
    a6 += __shfl_xor(a6, 16, 64); a6 += __shfl_xor(a6, 32, 64);
    a7 += __shfl_xor(a7, 16, 64); a7 += __shfl_xor(a7, 32, 64);
    if (q == 0) {   // lanes 0..15: (bl, og) -> feat half
        float inv = 1.0f / fmaxf((float)cnt, 1.0f);
        int cb = 8 * og;
        float4 f0, f1;
        f0.x = a0 * amp_w[cb]     * inv;  f0.y = a1 * amp_w[cb + 1] * inv;
        f0.z = a2 * amp_w[cb + 2] * inv;  f0.w = a3 * amp_w[cb + 3] * inv;
        f1.x = a4 * amp_w[cb + 4] * inv;  f1.y = a5 * amp_w[cb + 5] * inv;
        f1.z = a6 * amp_w[cb + 6] * inv;  f1.w = a7 * amp_w[cb + 7] * inv;
        *(float4*)&s_in[wv][bl][16 + cb]     = f0;
        *(float4*)&s_in[wv][bl][16 + cb + 4] = f1;
    }
    __syncthreads();

    // dense 32->32: thread (o4 = tid&7 -> 4 outputs, bl2 = (tid>>3)&7,
    // nl = tid>>6). Weight reads conflict-free ([kk][o] rows, stride 36).
    {
        int o4 = tid & 7, bl2 = (tid >> 3) & 7, nl = tid >> 6;
        float4 acc = *(const float4*)&b2[4 * o4];
        #pragma unroll
        for (int k4 = 0; k4 < 8; ++k4) {
            float4 iv = *(const float4*)&s_in[nl][bl2][4 * k4];
            float4 w0 = *(const float4*)&s_w2[(4 * k4)     * 36 + 4 * o4];
            float4 w1 = *(const float4*)&s_w2[(4 * k4 + 1) * 36 + 4 * o4];
            float4 wv2 = *(const float4*)&s_w2[(4 * k4 + 2) * 36 + 4 * o4];
            float4 w3 = *(const float4*)&s_w2[(4 * k4 + 3) * 36 + 4 * o4];
            acc.x += iv.x * w0.x + iv.y * w1.x + iv.z * wv2.x + iv.w * w3.x;
            acc.y += iv.x * w0.y + iv.y * w1.y + iv.z * wv2.y + iv.w * w3.y;
            acc.z += iv.x * w0.z + iv.y * w1.z + iv.z * wv2.z + iv.w * w3.z;
            acc.w += iv.x * w0.w + iv.y * w1.w + iv.z * wv2.w + iv.w * w3.w;
        }
        size_t ob = ((size_t)(bg * 8 + bl2) * N + (n0 + nl)) * 32;
        *(float4*)(out + ob + 4 * o4) = acc;
    }
}

// ---------------------------------------------------------------------------
extern "C" void kernel_launch(void* const* d_in, const int* in_sizes, int n_in,
                              void* d_out, int out_size, void* d_ws, size_t ws_size,
                              hipStream_t stream) {
    const float* X       = (const float*)d_in[0];
    const int*   ei1     = (const int*)  d_in[1];   // src=ei1, dst=ei1+E
    const float* ew1     = (const float*)d_in[2];
    const int*   ei2     = (const int*)  d_in[4];
    const float* ew2     = (const float*)d_in[5];
    const float* amp_w1  = (const float*)d_in[7];
    const float* gate_w1 = (const float*)d_in[8];
    const float* gate_b1 = (const float*)d_in[9];
    const float* w1      = (const float*)d_in[10];
    const float* b1      = (const float*)d_in[11];
    const float* amp_w2  = (const float*)d_in[12];
    const float* gate_w2 = (const float*)d_in[13];
    const float* gate_b2 = (const float*)d_in[14];
    const float* w2      = (const float*)d_in[15];
    const float* b2      = (const float*)d_in[16];
    float* out = (float*)d_out;

    // ws layout
    char* p = (char*)d_ws;
    ushort* yt     = (ushort*)p; p += (size_t)N * B * 16 * sizeof(ushort); // 5.12 MB
    ushort* htb    = (ushort*)p; p += (size_t)N * B * 16 * sizeof(ushort); // 5.12 MB
    float* xpart   = (float*)p;  p += (size_t)N * B * 16 * sizeof(float);  // 10.24 MB
    float* gi1     = (float*)p;  p += (size_t)N * B * sizeof(float);
    float* gj1     = (float*)p;  p += (size_t)N * B * sizeof(float);
    float* gi2     = (float*)p;  p += (size_t)N * B * sizeof(float);
    float* gj2     = (float*)p;  p += (size_t)N * B * sizeof(float);
    uint*  bucket1 = (uint*)p;   p += (size_t)N * CAP * sizeof(uint);      // 2.56 MB
    uint*  bucket2 = (uint*)p;   p += (size_t)N * CAP * sizeof(uint);      // 2.56 MB
    int*   bcount1 = (int*)p;    p += (size_t)N * sizeof(int);
    int*   bcount2 = (int*)p;    p += (size_t)N * sizeof(int);

    hipMemsetAsync(bcount1, 0, 2 * (size_t)N * sizeof(int), stream);
    prep_fused_kernel<<<2048, 256, 0, stream>>>(
        X, gate_w1, amp_w1, b1, ei1, ew1, ei2, ew2, w1,
        yt, xpart, gi1, gj1,
        bcount1, bucket1, bcount2, bucket2);

    agg1_kernel<<<N / 4, 256, 0, stream>>>(
        (const uint4*)yt, xpart, gi1, gj1, bcount1, bucket1,
        gate_w1, gate_b1, gate_w2, htb, gi2, gj2);

    // 2 batch-halves (bg slow): per-phase htb slice 2.56 MB, per-XCD L2-fit
    agg2_kernel<<<2 * (N / 4), 256, 0, stream>>>(
        (const uint4*)htb, gi2, gj2, bcount2, bucket2,
        gate_w2, gate_b2, amp_w2, w2, b2, out);
}